// Round 12
// baseline (693.140 us; speedup 1.0000x reference)
//
#include <hip/hip_runtime.h>
#include <hip/hip_cooperative_groups.h>

namespace cg = cooperative_groups;

#define NN 50000   // nodes
#define NE 800000  // edges
#define DD 128     // feature dim
#define NPAD 50176 // 196 * 256
#define NCH 196    // scan chunks of 256
#define CGRID 1008 // cooperative grid (multiple of 4; 4 blocks/CU at 33KB LDS)
#define NSB 49     // fallback scan blocks (1024 thr)
#define WGB 512    // fallback gemm-stream blocks
#define HBW 391    // fallback hist blocks appended
#define HB 782     // deep-fallback hist grid

// ws layout (ints): cnt[NPAD] | pos[NPAD] | bsum[256] | csr[NE] | g[NN*DD] f32

#define ACC4(A, V) { A.x += V.x; A.y += V.y; A.z += V.z; A.w += V.w; }

// 49-element exclusive prefix of bsum into sbase[] (fallback path, 1024-chunk)
#define BSUM_PREFIX(bsum, sbase)                                   \
  {                                                                \
    int tt = threadIdx.x;                                          \
    if (tt < 64) {                                                 \
      int b = (tt < NSB) ? bsum[tt] : 0;                           \
      int z = b;                                                   \
      _Pragma("unroll") for (int o = 1; o < 64; o <<= 1) {         \
        int w_ = __shfl_up(z, o);                                  \
        if (tt >= o) z += w_;                                      \
      }                                                            \
      sbase[tt] = z - b;                                           \
    }                                                              \
    __syncthreads();                                               \
  }

// ===========================================================================
// MEGA: one cooperative kernel, 5 phases, grid.sync() between.
//  P0 zero cnt | P1 hist + g=feat@W^T (quarter-W per block) | P2 scan |
//  P3 fill CSR | P4 gather-mean+bias+relu
// ===========================================================================
__global__ __launch_bounds__(256, 4) void k_mega(
    const float* __restrict__ feat, const float* __restrict__ W,
    const int* __restrict__ src, const int* __restrict__ dst,
    const float* __restrict__ bias, float* __restrict__ out,
    int* cnt, int* pos, int* bsum, int* csr, float* g) {
  __shared__ float4 Wq4[32 * 32];                                // 16KB
  __shared__ __attribute__((aligned(16))) float hs[4][8][DD];    // 16KB
  __shared__ int wsum[4];
  __shared__ int sbase[NCH];

  cg::grid_group grid = cg::this_grid();
  int tid = threadIdx.x;
  int bid = blockIdx.x;
  int nb = gridDim.x;

  // ---------------- phase 0: zero cnt ----------------
  for (int i = bid * 256 + tid; i < NPAD; i += nb * 256) cnt[i] = 0;
  grid.sync();

  // ---------------- phase 1: W-stage + hist + gemm ----------------
  int cgp = bid & 3;
  int col0 = cgp * 32;
  {
    const float4* W4 = (const float4*)W;
#pragma unroll
    for (int i = 0; i < 4; ++i) {
      int fidx = tid + (i << 8);  // 0..1023
      int c = fidx >> 5, kq = fidx & 31;
      Wq4[c * 32 + (kq ^ c)] = W4[(size_t)(col0 + c) * 32 + kq];
    }
  }
  // hist overlaps the W-stage LDS latency
  for (int idx = bid * 256 + tid; idx < NE / 4; idx += nb * 256) {
    int4 d = ((const int4*)dst)[idx];
    atomicAdd(&cnt[d.x], 1); atomicAdd(&cnt[d.y], 1);
    atomicAdd(&cnt[d.z], 1); atomicAdd(&cnt[d.w], 1);
  }
  __syncthreads();
  {
    int w = tid >> 6, lane = tid & 63;
    int hw = lane >> 5, c = lane & 31;
    const float2* feat2 = (const float2*)feat;
    for (int gid = (bid >> 2) * 4 + w; gid < NN / 8; gid += (nb >> 2) * 4) {
      int r0 = gid * 8;
#pragma unroll
      for (int r = 0; r < 8; ++r) {
        float2 v = feat2[(size_t)(r0 + r) * 64 + lane];
        hs[w][r][lane * 2] = v.x;
        hs[w][r][lane * 2 + 1] = v.y;
      }
      float a0 = 0.f, a1 = 0.f, a2 = 0.f, a3 = 0.f;
#pragma unroll 4
      for (int kc = 0; kc < 32; ++kc) {
        float4 w4 = Wq4[c * 32 + (kc ^ c)];
        float4 h0 = *(const float4*)&hs[w][hw * 4 + 0][kc * 4];
        float4 h1 = *(const float4*)&hs[w][hw * 4 + 1][kc * 4];
        float4 h2 = *(const float4*)&hs[w][hw * 4 + 2][kc * 4];
        float4 h3 = *(const float4*)&hs[w][hw * 4 + 3][kc * 4];
        a0 += h0.x * w4.x + h0.y * w4.y + h0.z * w4.z + h0.w * w4.w;
        a1 += h1.x * w4.x + h1.y * w4.y + h1.z * w4.z + h1.w * w4.w;
        a2 += h2.x * w4.x + h2.y * w4.y + h2.z * w4.z + h2.w * w4.w;
        a3 += h3.x * w4.x + h3.y * w4.y + h3.z * w4.z + h3.w * w4.w;
      }
      int rb = r0 + hw * 4;
      g[(size_t)(rb + 0) * DD + col0 + c] = a0;
      g[(size_t)(rb + 1) * DD + col0 + c] = a1;
      g[(size_t)(rb + 2) * DD + col0 + c] = a2;
      g[(size_t)(rb + 3) * DD + col0 + c] = a3;
    }
  }
  grid.sync();

  // ---------------- phase 2: block-local scan (256-chunks) ----------------
  for (int chunk = bid; chunk < NCH; chunk += nb) {
    int v = cnt[chunk * 256 + tid];
    int x = v;
#pragma unroll
    for (int o = 1; o < 64; o <<= 1) {
      int y = __shfl_up(x, o);
      if ((tid & 63) >= o) x += y;
    }
    if ((tid & 63) == 63) wsum[tid >> 6] = x;
    __syncthreads();
    if (tid == 0) {
      int s = 0;
#pragma unroll
      for (int i = 0; i < 4; ++i) { int t2 = wsum[i]; wsum[i] = s; s += t2; }
    }
    __syncthreads();
    pos[chunk * 256 + tid] = wsum[tid >> 6] + x - v;
    if (tid == 255) bsum[chunk] = wsum[3] + x;
    __syncthreads();
  }
  grid.sync();

  // ---------------- phase 3: sbase (196-wide prefix) + fill CSR ----------------
  if (tid < 64) {
    int b4[4] = {0, 0, 0, 0};
    int ssum = 0;
    if (tid < 49) {
#pragma unroll
      for (int i = 0; i < 4; ++i) { b4[i] = bsum[tid * 4 + i]; ssum += b4[i]; }
    }
    int z = ssum;
#pragma unroll
    for (int o = 1; o < 64; o <<= 1) {
      int y = __shfl_up(z, o);
      if (tid >= o) z += y;
    }
    int base = z - ssum;
    if (tid < 49) {
      int run = base;
#pragma unroll
      for (int i = 0; i < 4; ++i) { sbase[tid * 4 + i] = run; run += b4[i]; }
    }
  }
  __syncthreads();
  for (int idx = bid * 256 + tid; idx < NE / 4; idx += nb * 256) {
    int4 d = ((const int4*)dst)[idx];
    int4 s = ((const int4*)src)[idx];
    int p;
    p = atomicAdd(&pos[d.x], 1); csr[sbase[d.x >> 8] + p] = s.x;
    p = atomicAdd(&pos[d.y], 1); csr[sbase[d.y >> 8] + p] = s.y;
    p = atomicAdd(&pos[d.z], 1); csr[sbase[d.z >> 8] + p] = s.z;
    p = atomicAdd(&pos[d.w], 1); csr[sbase[d.w >> 8] + p] = s.w;
  }
  grid.sync();

  // ---------------- phase 4: gather-mean + bias + relu ----------------
  {
    int hw8 = tid >> 5, l32 = tid & 31;
    for (int n = bid * 8 + hw8; n < NN; n += nb * 8) {
      int c = cnt[n];
      int endg = sbase[n >> 8] + pos[n];
      int start = endg - c;
      float4 a0 = make_float4(0.f, 0.f, 0.f, 0.f), a1 = a0, a2 = a0, a3 = a0;
      for (int base = start; base < endg; base += 32) {
        int m = endg - base;
        if (m > 32) m = 32;
        int s = (l32 < m) ? csr[base + l32] : 0;
        int j = 0;
        for (; j + 8 <= m; j += 8) {
          int s0 = __shfl(s, j + 0, 32), s1 = __shfl(s, j + 1, 32),
              s2 = __shfl(s, j + 2, 32), s3 = __shfl(s, j + 3, 32),
              s4 = __shfl(s, j + 4, 32), s5 = __shfl(s, j + 5, 32),
              s6 = __shfl(s, j + 6, 32), s7 = __shfl(s, j + 7, 32);
          float4 v0 = ((const float4*)(g + (size_t)s0 * DD))[l32];
          float4 v1 = ((const float4*)(g + (size_t)s1 * DD))[l32];
          float4 v2 = ((const float4*)(g + (size_t)s2 * DD))[l32];
          float4 v3 = ((const float4*)(g + (size_t)s3 * DD))[l32];
          float4 v4 = ((const float4*)(g + (size_t)s4 * DD))[l32];
          float4 v5 = ((const float4*)(g + (size_t)s5 * DD))[l32];
          float4 v6 = ((const float4*)(g + (size_t)s6 * DD))[l32];
          float4 v7 = ((const float4*)(g + (size_t)s7 * DD))[l32];
          ACC4(a0, v0) ACC4(a1, v1) ACC4(a2, v2) ACC4(a3, v3)
          ACC4(a0, v4) ACC4(a1, v5) ACC4(a2, v6) ACC4(a3, v7)
        }
        for (; j < m; ++j) {
          int sj = __shfl(s, j, 32);
          float4 v = ((const float4*)(g + (size_t)sj * DD))[l32];
          ACC4(a0, v)
        }
      }
      a0.x += a1.x + a2.x + a3.x;
      a0.y += a1.y + a2.y + a3.y;
      a0.z += a1.z + a2.z + a3.z;
      a0.w += a1.w + a2.w + a3.w;
      float inv = 1.0f / fmaxf((float)c, 1.0f);
      float4 b4 = ((const float4*)bias)[l32];
      float4 o;
      o.x = fmaxf(a0.x * inv + b4.x, 0.f);
      o.y = fmaxf(a0.y * inv + b4.y, 0.f);
      o.z = fmaxf(a0.z * inv + b4.z, 0.f);
      o.w = fmaxf(a0.w * inv + b4.w, 0.f);
      ((float4*)(out + (size_t)n * DD))[l32] = o;
    }
  }
}

// ===========================================================================
// Fallback pipeline (r10, proven 240us) — used if cooperative launch is
// unavailable. Identical kernels; csr offset by 256-int bsum region.
// ===========================================================================
__global__ __launch_bounds__(256) void k_gemm_hist(
    const float* __restrict__ feat, const float* __restrict__ W,
    float* __restrict__ g, const int* __restrict__ dst, int* __restrict__ cnt) {
  __shared__ float4 Wc4[DD * 32];
  __shared__ float hs[4][8][DD];
  int tid = threadIdx.x;
  int bid = blockIdx.x;

  if (bid >= WGB) {
    int idx = (bid - WGB) * 256 + tid;
    if (idx < NE / 8) {
      const int4* d4 = (const int4*)dst;
      int4 a = d4[idx * 2];
      int4 b = d4[idx * 2 + 1];
      atomicAdd(&cnt[a.x], 1); atomicAdd(&cnt[a.y], 1);
      atomicAdd(&cnt[a.z], 1); atomicAdd(&cnt[a.w], 1);
      atomicAdd(&cnt[b.x], 1); atomicAdd(&cnt[b.y], 1);
      atomicAdd(&cnt[b.z], 1); atomicAdd(&cnt[b.w], 1);
    }
    return;
  }
  {
    const float4* W4 = (const float4*)W;
#pragma unroll
    for (int i = 0; i < 16; ++i) {
      int fidx = tid + (i << 8);
      int c = fidx >> 5, kq = fidx & 31;
      Wc4[c * 32 + (kq ^ (c & 31))] = W4[fidx];
    }
  }
  __syncthreads();
  int w = tid >> 6, lane = tid & 63;
  int s = lane & 31;
  const float2* feat2 = (const float2*)feat;
  for (int gid = bid * 4 + w; gid < NN / 8; gid += WGB * 4) {
    int r0 = gid * 8;
#pragma unroll
    for (int r = 0; r < 8; ++r) {
      float2 v = feat2[(size_t)(r0 + r) * 64 + lane];
      hs[w][r][lane * 2] = v.x;
      hs[w][r][lane * 2 + 1] = v.y;
    }
    float2 acc[8] = {};
#pragma unroll 2
    for (int kc = 0; kc < 32; ++kc) {
      float4 w0 = Wc4[lane * 32 + (kc ^ s)];
      float4 w1 = Wc4[(lane + 64) * 32 + (kc ^ s)];
#pragma unroll
      for (int r = 0; r < 8; ++r) {
        float4 h = *(const float4*)&hs[w][r][kc * 4];
        acc[r].x += h.x * w0.x; acc[r].x += h.y * w0.y;
        acc[r].x += h.z * w0.z; acc[r].x += h.w * w0.w;
        acc[r].y += h.x * w1.x; acc[r].y += h.y * w1.y;
        acc[r].y += h.z * w1.z; acc[r].y += h.w * w1.w;
      }
    }
#pragma unroll
    for (int r = 0; r < 8; ++r) {
      g[(size_t)(r0 + r) * DD + lane] = acc[r].x;
      g[(size_t)(r0 + r) * DD + lane + 64] = acc[r].y;
    }
  }
}

__global__ __launch_bounds__(1024) void k_scan(const int* __restrict__ cnt,
                                               int* __restrict__ pos,
                                               int* __restrict__ bsum) {
  __shared__ int wsum[16];
  int t = threadIdx.x;
  int gidx = blockIdx.x * 1024 + t;
  int v = cnt[gidx];
  int x = v;
#pragma unroll
  for (int o = 1; o < 64; o <<= 1) {
    int y = __shfl_up(x, o);
    if ((t & 63) >= o) x += y;
  }
  if ((t & 63) == 63) wsum[t >> 6] = x;
  __syncthreads();
  if (t < 64) {
    int y = (t < 16) ? wsum[t] : 0;
    int z = y;
#pragma unroll
    for (int o = 1; o < 16; o <<= 1) {
      int w = __shfl_up(z, o);
      if (t >= o) z += w;
    }
    if (t < 16) wsum[t] = z - y;
  }
  __syncthreads();
  pos[gidx] = wsum[t >> 6] + x - v;
  if (t == 1023) bsum[blockIdx.x] = wsum[15] + x;
}

__global__ __launch_bounds__(256) void k_fill(const int* __restrict__ src,
                                              const int* __restrict__ dst,
                                              int* __restrict__ pos,
                                              int* __restrict__ csr,
                                              const int* __restrict__ bsum) {
  __shared__ int sbase[64];
  BSUM_PREFIX(bsum, sbase)
  int idx = blockIdx.x * 256 + threadIdx.x;
  if (idx < NE / 4) {
    int4 d = ((const int4*)dst)[idx];
    int4 s = ((const int4*)src)[idx];
    int p;
    p = atomicAdd(&pos[d.x], 1); csr[sbase[d.x >> 10] + p] = s.x;
    p = atomicAdd(&pos[d.y], 1); csr[sbase[d.y >> 10] + p] = s.y;
    p = atomicAdd(&pos[d.z], 1); csr[sbase[d.z >> 10] + p] = s.z;
    p = atomicAdd(&pos[d.w], 1); csr[sbase[d.w >> 10] + p] = s.w;
  }
}

__global__ __launch_bounds__(256) void k_gmean(const float* __restrict__ g,
                                               const int* __restrict__ csr,
                                               const int* __restrict__ pos,
                                               const int* __restrict__ cnt,
                                               const int* __restrict__ bsum,
                                               const float* __restrict__ bias,
                                               float* __restrict__ out) {
  __shared__ int sbase[64];
  BSUM_PREFIX(bsum, sbase)
  int tid = threadIdx.x;
  int hw = tid >> 5, l32 = tid & 31;
  int n = blockIdx.x * 8 + hw;
  int c = cnt[n];
  int endg = sbase[n >> 10] + pos[n];
  int start = endg - c;
  float4 a0 = make_float4(0.f, 0.f, 0.f, 0.f), a1 = a0, a2 = a0, a3 = a0;
  for (int base = start; base < endg; base += 32) {
    int m = endg - base;
    if (m > 32) m = 32;
    int s = (l32 < m) ? csr[base + l32] : 0;
    int j = 0;
    for (; j + 8 <= m; j += 8) {
      int s0 = __shfl(s, j + 0, 32), s1 = __shfl(s, j + 1, 32),
          s2 = __shfl(s, j + 2, 32), s3 = __shfl(s, j + 3, 32),
          s4 = __shfl(s, j + 4, 32), s5 = __shfl(s, j + 5, 32),
          s6 = __shfl(s, j + 6, 32), s7 = __shfl(s, j + 7, 32);
      float4 v0 = ((const float4*)(g + (size_t)s0 * DD))[l32];
      float4 v1 = ((const float4*)(g + (size_t)s1 * DD))[l32];
      float4 v2 = ((const float4*)(g + (size_t)s2 * DD))[l32];
      float4 v3 = ((const float4*)(g + (size_t)s3 * DD))[l32];
      float4 v4 = ((const float4*)(g + (size_t)s4 * DD))[l32];
      float4 v5 = ((const float4*)(g + (size_t)s5 * DD))[l32];
      float4 v6 = ((const float4*)(g + (size_t)s6 * DD))[l32];
      float4 v7 = ((const float4*)(g + (size_t)s7 * DD))[l32];
      ACC4(a0, v0) ACC4(a1, v1) ACC4(a2, v2) ACC4(a3, v3)
      ACC4(a0, v4) ACC4(a1, v5) ACC4(a2, v6) ACC4(a3, v7)
    }
    for (; j < m; ++j) {
      int sj = __shfl(s, j, 32);
      float4 v = ((const float4*)(g + (size_t)sj * DD))[l32];
      ACC4(a0, v)
    }
  }
  a0.x += a1.x + a2.x + a3.x;
  a0.y += a1.y + a2.y + a3.y;
  a0.z += a1.z + a2.z + a3.z;
  a0.w += a1.w + a2.w + a3.w;
  float inv = 1.0f / fmaxf((float)c, 1.0f);
  float4 b4 = ((const float4*)bias)[l32];
  float4 o;
  o.x = fmaxf(a0.x * inv + b4.x, 0.f);
  o.y = fmaxf(a0.y * inv + b4.y, 0.f);
  o.z = fmaxf(a0.z * inv + b4.z, 0.f);
  o.w = fmaxf(a0.w * inv + b4.w, 0.f);
  ((float4*)(out + (size_t)n * DD))[l32] = o;
}

__global__ __launch_bounds__(128) void k_hist(const int* __restrict__ dst,
                                              int* __restrict__ cnt) {
  int idx = blockIdx.x * 128 + threadIdx.x;
  if (idx < NE / 8) {
    const int4* d4 = (const int4*)dst;
    int4 a = d4[idx * 2];
    int4 b = d4[idx * 2 + 1];
    atomicAdd(&cnt[a.x], 1); atomicAdd(&cnt[a.y], 1);
    atomicAdd(&cnt[a.z], 1); atomicAdd(&cnt[a.w], 1);
    atomicAdd(&cnt[b.x], 1); atomicAdd(&cnt[b.y], 1);
    atomicAdd(&cnt[b.z], 1); atomicAdd(&cnt[b.w], 1);
  }
}

__global__ __launch_bounds__(256) void k_gsum(const float* __restrict__ feat,
                                              const int* __restrict__ csr,
                                              const int* __restrict__ pos,
                                              const int* __restrict__ cnt,
                                              const int* __restrict__ bsum,
                                              float* __restrict__ out) {
  __shared__ int sbase[64];
  BSUM_PREFIX(bsum, sbase)
  int tid = threadIdx.x;
  int hw = tid >> 5, l32 = tid & 31;
  int n = blockIdx.x * 8 + hw;
  int c = cnt[n];
  int endg = sbase[n >> 10] + pos[n];
  int start = endg - c;
  float4 a0 = make_float4(0.f, 0.f, 0.f, 0.f), a1 = a0;
  for (int base = start; base < endg; base += 32) {
    int m = endg - base;
    if (m > 32) m = 32;
    int s = (l32 < m) ? csr[base + l32] : 0;
    for (int j = 0; j < m; ++j) {
      int sj = __shfl(s, j, 32);
      float4 v = ((const float4*)(feat + (size_t)sj * DD))[l32];
      if (j & 1) { ACC4(a1, v) } else { ACC4(a0, v) }
    }
  }
  a0.x += a1.x; a0.y += a1.y; a0.z += a1.z; a0.w += a1.w;
  ((float4*)(out + (size_t)n * DD))[l32] = a0;
}

__global__ __launch_bounds__(256) void k_gemm_inplace(float* __restrict__ io,
                                                      const int* __restrict__ cnt,
                                                      const float* __restrict__ W,
                                                      const float* __restrict__ bias) {
  __shared__ float Wt[64][132];
  __shared__ __attribute__((aligned(16))) float hs[64][72];
  int tid = threadIdx.x;
  int row0 = blockIdx.x * 64;
  int tc = tid & 31;
  int tr = tid >> 5;
  float acc[8][4] = {};
  for (int p = 0; p < 2; ++p) {
    if (p) __syncthreads();
    for (int i = 0; i < 8; ++i) {
      int fidx = tid + (i << 8);
      int c = fidx >> 4;
      int kq = fidx & 15;
      float4 w = ((const float4*)W)[c * 32 + p * 16 + kq];
      int kk = kq << 2;
      Wt[kk + 0][c ^ (((kk + 0) & 31) << 2)] = w.x;
      Wt[kk + 1][c ^ (((kk + 1) & 31) << 2)] = w.y;
      Wt[kk + 2][c ^ (((kk + 2) & 31) << 2)] = w.z;
      Wt[kk + 3][c ^ (((kk + 3) & 31) << 2)] = w.w;
    }
    for (int i = 0; i < 4; ++i) {
      int fidx = tid + (i << 8);
      int r = fidx & 63;
      int kq = fidx >> 6;
      int grow = row0 + r;
      float4 v = make_float4(0.f, 0.f, 0.f, 0.f);
      if (grow < NN) {
        v = ((const float4*)io)[(size_t)grow * 32 + p * 16 + kq];
        float inv = 1.0f / fmaxf((float)cnt[grow], 1.0f);
        v.x *= inv; v.y *= inv; v.z *= inv; v.w *= inv;
      }
      int kk = kq << 2;
      hs[kk + 0][r] = v.x;
      hs[kk + 1][r] = v.y;
      hs[kk + 2][r] = v.z;
      hs[kk + 3][r] = v.w;
    }
    __syncthreads();
#pragma unroll 4
    for (int kk = 0; kk < 64; ++kk) {
      float4 w4 = *(const float4*)&Wt[kk][(tc << 2) ^ ((kk & 31) << 2)];
      float4 h0 = *(const float4*)&hs[kk][tr << 3];
      float4 h1 = *(const float4*)&hs[kk][(tr << 3) + 4];
      acc[0][0] += h0.x * w4.x; acc[0][1] += h0.x * w4.y; acc[0][2] += h0.x * w4.z; acc[0][3] += h0.x * w4.w;
      acc[1][0] += h0.y * w4.x; acc[1][1] += h0.y * w4.y; acc[1][2] += h0.y * w4.z; acc[1][3] += h0.y * w4.w;
      acc[2][0] += h0.z * w4.x; acc[2][1] += h0.z * w4.y; acc[2][2] += h0.z * w4.z; acc[2][3] += h0.z * w4.w;
      acc[3][0] += h0.w * w4.x; acc[3][1] += h0.w * w4.y; acc[3][2] += h0.w * w4.z; acc[3][3] += h0.w * w4.w;
      acc[4][0] += h1.x * w4.x; acc[4][1] += h1.x * w4.y; acc[4][2] += h1.x * w4.z; acc[4][3] += h1.x * w4.w;
      acc[5][0] += h1.y * w4.x; acc[5][1] += h1.y * w4.y; acc[5][2] += h1.y * w4.z; acc[5][3] += h1.y * w4.w;
      acc[6][0] += h1.z * w4.x; acc[6][1] += h1.z * w4.y; acc[6][2] += h1.z * w4.z; acc[6][3] += h1.z * w4.w;
      acc[7][0] += h1.w * w4.x; acc[7][1] += h1.w * w4.y; acc[7][2] += h1.w * w4.z; acc[7][3] += h1.w * w4.w;
    }
  }
  float4 b4 = ((const float4*)bias)[tc];
#pragma unroll
  for (int r = 0; r < 8; ++r) {
    int row = row0 + (tr << 3) + r;
    if (row < NN) {
      float4 o;
      o.x = fmaxf(acc[r][0] + b4.x, 0.f);
      o.y = fmaxf(acc[r][1] + b4.y, 0.f);
      o.z = fmaxf(acc[r][2] + b4.z, 0.f);
      o.w = fmaxf(acc[r][3] + b4.w, 0.f);
      ((float4*)(io + (size_t)row * DD))[tc] = o;
    }
  }
}

extern "C" void kernel_launch(void* const* d_in, const int* in_sizes, int n_in,
                              void* d_out, int out_size, void* d_ws, size_t ws_size,
                              hipStream_t stream) {
  const float* feature = (const float*)d_in[0];
  const int*   src     = (const int*)d_in[1];
  const int*   dst     = (const int*)d_in[2];
  const float* W       = (const float*)d_in[3];
  const float* bias    = (const float*)d_in[4];
  float* out = (float*)d_out;

  int* cnt  = (int*)d_ws;
  int* pos  = cnt + NPAD;
  int* bsum = pos + NPAD;
  int* csr  = bsum + 256;
  float* g  = (float*)(csr + NE);

  size_t need_main = (size_t)(2 * NPAD + 256 + NE) * 4 + (size_t)NN * DD * 4;

  int coop = 0, dev = 0;
  hipGetDevice(&dev);
  hipDeviceGetAttribute(&coop, hipDeviceAttributeCooperativeLaunch, dev);

  if (coop && ws_size >= need_main) {
    // single cooperative dispatch: all 5 phases, zero launch gaps
    void* args[] = {(void*)&feature, (void*)&W, (void*)&src, (void*)&dst,
                    (void*)&bias, (void*)&out, (void*)&cnt, (void*)&pos,
                    (void*)&bsum, (void*)&csr, (void*)&g};
    hipError_t e = hipLaunchCooperativeKernel((const void*)k_mega, dim3(CGRID),
                                              dim3(256), args, 0, stream);
    if (e == hipSuccess) return;
    // fall through to classic pipeline on failure
  }

  hipMemsetAsync(cnt, 0, NPAD * sizeof(int), stream);
  if (ws_size >= need_main) {
    hipLaunchKernelGGL(k_gemm_hist, dim3(WGB + HBW), dim3(256), 0, stream,
                       feature, W, g, dst, cnt);
    hipLaunchKernelGGL(k_scan, dim3(NSB), dim3(1024), 0, stream, cnt, pos, bsum);
    hipLaunchKernelGGL(k_fill, dim3((NE / 4 + 255) / 256), dim3(256), 0, stream,
                       src, dst, pos, csr, bsum);
    hipLaunchKernelGGL(k_gmean, dim3(NN / 8), dim3(256), 0, stream,
                       g, csr, pos, cnt, bsum, bias, out);
  } else {
    hipLaunchKernelGGL(k_hist, dim3(HB), dim3(128), 0, stream, dst, cnt);
    hipLaunchKernelGGL(k_scan, dim3(NSB), dim3(1024), 0, stream, cnt, pos, bsum);
    hipLaunchKernelGGL(k_fill, dim3((NE / 4 + 255) / 256), dim3(256), 0, stream,
                       src, dst, pos, csr, bsum);
    hipLaunchKernelGGL(k_gsum, dim3(NN / 8), dim3(256), 0, stream,
                       feature, csr, pos, cnt, bsum, out);
    hipLaunchKernelGGL(k_gemm_inplace, dim3((NN + 63) / 64), dim3(256), 0,
                       stream, out, cnt, W, bias);
  }
}